// Round 29
// baseline (28.112 us; speedup 1.0000x reference)
//
#include <hip/hip_runtime.h>

// ChamferDistance: B=4, N=M=8192, fp32 3-D points.
// R29: R28 with the permlane32_swap OUTPUT FIXED (use b, not a).
// R28 failure (absmax 1.27) diagnosed the semantic: the instruction swaps
// dst.high32 <-> src.low32. With a=b=w: a={w.lo,w.lo} (tile 2p duplicated —
// the observed miss of all odd tiles), b={w.hi,w.hi} (tile 2p+1 duplicated —
// exactly what MFMA#2 needs; the high half is don't-care since A's kg=1
// lanes are zero). One-line fix: return b.
// Structure (R27 champion + pair-read): fp16 K=7, 16 B/point, ONE
// ds_read_b128 per TWO tiles (lane l reads point pg*64+l, 1 KB contiguous,
// conflict-free) + 4 permlane + 2 MFMA + 16 min3 per pair. LDS-pipe floor
// 10.2 -> 5.1 µs. Geometry: 1024 thr, 256 rows/block, wave = rt(w&7) x
// col-half(w>>3), 8 stages x 2 barriers, direct store, ONE launch,
// no workspace/init/atomics.
// A=[-2x(3), n1h, n1l, 1, 1, 0] fp16 (kg=1 lanes zero);
// B=[y(3), 1, 1, n2h, n2l, 0] fp16.
// C layout 32x32 (dtype-independent): col=lane&31, row=(r&3)+8*(r>>2)+4*kg.

typedef _Float16 half8 __attribute__((ext_vector_type(8)));
typedef float    f32x16 __attribute__((ext_vector_type(16)));

#define B_       4
#define NPT      8192
#define THREADS  1024
#define NROWBLK  32              // 256 rows per block
#define STAGEPTS 1024            // B points per LDS stage (16 KB packed)
#define NSTAGE   (NPT / STAGEPTS)    // 8
#define PINF_I   0x7f800000

__device__ __forceinline__ unsigned pkh(_Float16 a, _Float16 b) {
    union { _Float16 h; unsigned short u; } ua, ub;
    ua.h = a; ub.h = b;
    return (((unsigned)ub.u) << 16) | ua.u;
}

// Pack one row-point into the lane's A-fragment (kg=1 lanes: zeros -> kills
// the k8-15 half of the MFMA regardless of B's upper-half contents).
__device__ __forceinline__ half8 packA(const float* __restrict__ p, int kg) {
    half8 r = {};
    if (kg == 0) {
        float x0 = p[0], x1 = p[1], x2 = p[2];
        float n = x0*x0 + x1*x1 + x2*x2;
        _Float16 nh = (_Float16)n;
        _Float16 nl = (_Float16)(n - (float)nh);
        r[0] = (_Float16)(-2.f * x0);
        r[1] = (_Float16)(-2.f * x1);
        r[2] = (_Float16)(-2.f * x2);
        r[3] = nh; r[4] = nl;
        r[5] = (_Float16)1.f; r[6] = (_Float16)1.f;
        r[7] = (_Float16)0.f;
    }
    return r;
}

// After swap, b.low32 = w.high32 (R28 diagnosis: inst swaps dst.hi <-> src.lo).
__device__ __forceinline__ unsigned lane_half_swap(unsigned w) {
    unsigned a = w, b = w;
    asm volatile("v_permlane32_swap_b32 %0, %1" : "+v"(a), "+v"(b));
    return b;
}

__global__ __launch_bounds__(THREADS, 4)   // 16 waves/block, 1 block/CU
void cd_fused(const float* __restrict__ xyz1, const float* __restrict__ xyz2,
              float* __restrict__ out) {
    __shared__ uint4 ysh[2048];            // 32 KB (stage uses 16 KB; csh 32 KB)

    int bid = blockIdx.x;
    const int rb   = bid & (NROWBLK - 1);  bid >>= 5;
    const int b    = bid & (B_ - 1);       bid >>= 2;
    const int pass = bid;                   // 0: dist1 (rows=cloud1), 1: dist2

    const float* __restrict__ xa = pass ? xyz2 : xyz1;   // row cloud
    const float* __restrict__ xb = pass ? xyz1 : xyz2;   // col cloud
    float* __restrict__ o = out + (size_t)pass * B_ * NPT;

    const int tid  = threadIdx.x;
    const int lane = tid & 63;
    const int w    = tid >> 6;             // 0..15
    const int rt   = w & 7;                // row-tile within block (8)
    const int h    = w >> 3;               // column half (0 or 1)
    const int l31  = lane & 31;
    const int kg   = lane >> 5;

    const size_t bbase = (size_t)b * NPT;
    const int    myRow = rb * 256 + rt * 32;

    // In-register A fragment (fp16, kg=1 -> zeros).
    half8 afrag = packA(xa + (bbase + myRow + l31) * 3, kg);

    f32x16 rmin;
    #pragma unroll
    for (int r = 0; r < 16; ++r) rmin[r] = __int_as_float(PINF_I);

    const half8* bsh = (const half8*)ysh;

    for (int s = 0; s < NSTAGE; ++s) {
        // Pack 1024 B points into LDS (ONE per thread), 16 B per point:
        // [y0, y1, y2, 1, 1, n2h, n2l, 0] as fp16.
        {
            const int p = tid;
            const float* yp = xb + (bbase + (size_t)s * STAGEPTS + p) * 3;
            float y0 = yp[0], y1 = yp[1], y2 = yp[2];
            float n = y0*y0 + y1*y1 + y2*y2;
            _Float16 nh = (_Float16)n;
            _Float16 nl = (_Float16)(n - (float)nh);
            const _Float16 one = (_Float16)1.f;
            ysh[p] = make_uint4(
                pkh((_Float16)y0, (_Float16)y1),
                pkh((_Float16)y2, one),
                pkh(one, nh),
                pkh(nl, (_Float16)0.f));
        }
        __syncthreads();

        // This wave's column half: 16 tiles = 8 pair-groups.
        // Per pair: 1 ds_read_b128 (64 distinct points = 2 tiles, 1 KB
        // contiguous) + 4 permlane swaps + 2 MFMA + 16 min3.
        #pragma unroll
        for (int pr = 0; pr < 8; ++pr) {
            const int pg = h * 8 + pr;
            half8 bf = bsh[pg * 64 + lane];

            union { half8 h8; uint4 u4; } cv, cw;
            cv.h8 = bf;
            cw.u4.x = lane_half_swap(cv.u4.x);
            cw.u4.y = lane_half_swap(cv.u4.y);
            cw.u4.z = lane_half_swap(cv.u4.z);
            cw.u4.w = lane_half_swap(cv.u4.w);
            half8 bf2 = cw.h8;               // tile 2pg+1 in low lanes

            f32x16 z = {0.f};
            f32x16 accX = __builtin_amdgcn_mfma_f32_32x32x16_f16(afrag, bf,  z, 0, 0, 0);
            f32x16 accY = __builtin_amdgcn_mfma_f32_32x32x16_f16(afrag, bf2, z, 0, 0, 0);
            #pragma unroll
            for (int r = 0; r < 16; ++r)
                rmin[r] = fminf(fminf(accX[r], accY[r]), rmin[r]);   // v_min3_f32
        }
        __syncthreads();
    }

    // Cross-half combine via LDS (reuse ysh; [rt][r][lane] = conflict-free).
    float* csh = (float*)ysh;              // 8 * 16 * 64 floats = 32 KB
    if (h == 1) {
        #pragma unroll
        for (int r = 0; r < 16; ++r)
            csh[rt * 1024 + r * 64 + lane] = rmin[r];
    }
    __syncthreads();
    if (h == 0) {
        #pragma unroll
        for (int r = 0; r < 16; ++r) {
            float v = fminf(rmin[r], csh[rt * 1024 + r * 64 + lane]);
            v = fminf(v, __shfl_xor(v, 1, 64));
            v = fminf(v, __shfl_xor(v, 2, 64));
            v = fminf(v, __shfl_xor(v, 4, 64));
            v = fminf(v, __shfl_xor(v, 8, 64));
            v = fminf(v, __shfl_xor(v, 16, 64));
            if (l31 == 0) {
                int row = myRow + (r & 3) + 8 * (r >> 2) + 4 * kg;
                o[bbase + row] = fmaxf(v, 0.f);
            }
        }
    }
}

extern "C" void kernel_launch(void* const* d_in, const int* in_sizes, int n_in,
                              void* d_out, int out_size, void* d_ws, size_t ws_size,
                              hipStream_t stream) {
    const float* xyz1 = (const float*)d_in[0];
    const float* xyz2 = (const float*)d_in[1];
    // ONE launch, no workspace, no init, no atomics.
    cd_fused<<<2 * B_ * NROWBLK, THREADS, 0, stream>>>(xyz1, xyz2, (float*)d_out);
}

// Round 30
// 27.341 us; speedup vs baseline: 1.0282x; 1.0282x over previous
//
#include <hip/hip_runtime.h>

// ChamferDistance: B=4, N=M=8192, fp32 3-D points.
// R30: 2 BLOCKS/CU + 8 waves/SIMD on the fp16 K=7 structure.
// R29 post-mortem: pair-read passed (permlane b.lo<-dst.hi verified) but
// 28.1 > R27's 25.4. Pattern across R25/R26/R29: every single-pipe reduction
// HURTS -> no pipe is binding; R27 is dependency-latency-bound at 4 waves/
// SIMD with 1 block/CU (no barrier overlap). This round adds the one missing
// mechanism: a SECOND block per CU (barrier overlap + 8 waves/SIMD).
// fp16 enables it: 16 KB stage x 2 blocks = 32 KB LDS; fp16 pack (~10 ops)
// makes the 2x pack redundancy ~0.4 µs (R21's killer was the 45-op bf16
// pack). To fit the <=64-VGPR bucket (8 waves/SIMD, m69): NO min3 pairing —
// single-tile loop, live ~55 regs, launch_bounds(1024,8).
// Geometry: 1024 thr, 128 rows/block, wave = rt(w&3) x col-quarter(w>>2),
// 8 tiles/stage/wave, 8 stages x 2 barriers, grid 512 = 2 blocks/CU.
// Quarter-combine: LDS int-punned atomicMin (R26-proven), q==0 stores.
// Math verified since R4/R27 (absmax 0.0156): fp16 K=7, zero-A-upper-half;
// A=[-2x(3), n1h, n1l, 1, 1, 0]; B=[y(3), 1, 1, n2h, n2l, 0].
// C layout 32x32 (dtype-independent): col=lane&31, row=(r&3)+8*(r>>2)+4*kg.

typedef _Float16 half8 __attribute__((ext_vector_type(8)));
typedef float    f32x16 __attribute__((ext_vector_type(16)));

#define B_       4
#define NPT      8192
#define THREADS  1024
#define NROWBLK  64              // 128 rows per block
#define STAGEPTS 1024            // B points per LDS stage (16 KB packed)
#define NSTAGE   (NPT / STAGEPTS)    // 8
#define PINF_I   0x7f800000

__device__ __forceinline__ unsigned pkh(_Float16 a, _Float16 b) {
    union { _Float16 h; unsigned short u; } ua, ub;
    ua.h = a; ub.h = b;
    return (((unsigned)ub.u) << 16) | ua.u;
}

// Pack one row-point into the lane's A-fragment (kg=1 lanes: zeros -> kills
// the k8-15 half of the MFMA regardless of B's upper-half contents).
__device__ __forceinline__ half8 packA(const float* __restrict__ p, int kg) {
    half8 r = {};
    if (kg == 0) {
        float x0 = p[0], x1 = p[1], x2 = p[2];
        float n = x0*x0 + x1*x1 + x2*x2;
        _Float16 nh = (_Float16)n;
        _Float16 nl = (_Float16)(n - (float)nh);
        r[0] = (_Float16)(-2.f * x0);
        r[1] = (_Float16)(-2.f * x1);
        r[2] = (_Float16)(-2.f * x2);
        r[3] = nh; r[4] = nl;
        r[5] = (_Float16)1.f; r[6] = (_Float16)1.f;
        r[7] = (_Float16)0.f;
    }
    return r;
}

__global__ __launch_bounds__(THREADS, 8)   // <=64-VGPR bucket -> 8 waves/SIMD
void cd_fused(const float* __restrict__ xyz1, const float* __restrict__ xyz2,
              float* __restrict__ out) {
    __shared__ uint4 ysh[STAGEPTS];        // 16 KB: stage; csh overlays (16 KB)

    int bid = blockIdx.x;
    const int rb   = bid & (NROWBLK - 1);  bid >>= 6;
    const int b    = bid & (B_ - 1);       bid >>= 2;
    const int pass = bid;                   // 0: dist1 (rows=cloud1), 1: dist2

    const float* __restrict__ xa = pass ? xyz2 : xyz1;   // row cloud
    const float* __restrict__ xb = pass ? xyz1 : xyz2;   // col cloud
    float* __restrict__ o = out + (size_t)pass * B_ * NPT;

    const int tid  = threadIdx.x;
    const int lane = tid & 63;
    const int w    = tid >> 6;             // 0..15
    const int rt   = w & 3;                // row-tile within block (4)
    const int q    = w >> 2;               // column quarter (0..3)
    const int l31  = lane & 31;
    const int kg   = lane >> 5;

    const size_t bbase = (size_t)b * NPT;
    const int    myRow = rb * 128 + rt * 32;

    // In-register A fragment (fp16, kg=1 -> zeros).
    half8 afrag = packA(xa + (bbase + myRow + l31) * 3, kg);

    f32x16 rmin;
    #pragma unroll
    for (int r = 0; r < 16; ++r) rmin[r] = __int_as_float(PINF_I);

    const half8* bsh = (const half8*)ysh;

    for (int s = 0; s < NSTAGE; ++s) {
        // Pack 1024 B points into LDS (ONE per thread), 16 B per point:
        // [y0, y1, y2, 1, 1, n2h, n2l, 0] as fp16.
        {
            const int p = tid;
            const float* yp = xb + (bbase + (size_t)s * STAGEPTS + p) * 3;
            float y0 = yp[0], y1 = yp[1], y2 = yp[2];
            float n = y0*y0 + y1*y1 + y2*y2;
            _Float16 nh = (_Float16)n;
            _Float16 nl = (_Float16)(n - (float)nh);
            const _Float16 one = (_Float16)1.f;
            ysh[p] = make_uint4(
                pkh((_Float16)y0, (_Float16)y1),
                pkh((_Float16)y2, one),
                pkh(one, nh),
                pkh(nl, (_Float16)0.f));
        }
        __syncthreads();

        // This wave's column quarter: 8 tiles, single acc live (reg budget).
        #pragma unroll
        for (int i = 0; i < 8; ++i) {
            const int t = q * 8 + i;
            half8 bf = bsh[t * 32 + l31];   // kg-pairs share addr: broadcast
            f32x16 z = {0.f};
            f32x16 acc = __builtin_amdgcn_mfma_f32_32x32x16_f16(afrag, bf, z, 0, 0, 0);
            #pragma unroll
            for (int r = 0; r < 16; ++r) rmin[r] = fminf(rmin[r], acc[r]);
        }
        __syncthreads();
    }

    // Cross-quarter combine: int-punned LDS atomicMin into 16 KB csh
    // (4 rt x 16 r x 64 lanes = 4096 ints, overlays ysh).
    int* csh = (int*)ysh;
    #pragma unroll
    for (int j = 0; j < 4; ++j) csh[tid * 4 + j] = PINF_I;
    __syncthreads();
    #pragma unroll
    for (int r = 0; r < 16; ++r)
        atomicMin(&csh[rt * 1024 + r * 64 + lane],
                  __float_as_int(fmaxf(rmin[r], 0.f)));
    __syncthreads();

    // q==0 waves: butterfly each combined row-min across 32 col-slots, store.
    if (q == 0) {
        #pragma unroll
        for (int r = 0; r < 16; ++r) {
            float v = __int_as_float(csh[rt * 1024 + r * 64 + lane]);
            v = fminf(v, __shfl_xor(v, 1, 64));
            v = fminf(v, __shfl_xor(v, 2, 64));
            v = fminf(v, __shfl_xor(v, 4, 64));
            v = fminf(v, __shfl_xor(v, 8, 64));
            v = fminf(v, __shfl_xor(v, 16, 64));
            if (l31 == 0) {
                int row = myRow + (r & 3) + 8 * (r >> 2) + 4 * kg;
                o[bbase + row] = v;   // already clamped >= 0
            }
        }
    }
}

extern "C" void kernel_launch(void* const* d_in, const int* in_sizes, int n_in,
                              void* d_out, int out_size, void* d_ws, size_t ws_size,
                              hipStream_t stream) {
    const float* xyz1 = (const float*)d_in[0];
    const float* xyz2 = (const float*)d_in[1];
    // ONE launch, no workspace, no init, no global atomics.
    cd_fused<<<2 * B_ * NROWBLK, THREADS, 0, stream>>>(xyz1, xyz2, (float*)d_out);
}